// Round 14
// baseline (190.565 us; speedup 1.0000x reference)
//
#include <hip/hip_runtime.h>

#define SS 2048
#define NH 16
#define NKV 4
#define HD 64

typedef __bf16 bf16;
typedef __bf16 bf16x8 __attribute__((ext_vector_type(8)));
typedef float f32x4 __attribute__((ext_vector_type(4)));

// softmax scale folded into Q at the QKV epilogue: (1/sqrt(64)) * log2(e)
#define SM_SCALE 0.18033688011f

__device__ __forceinline__ void gl_lds16(const bf16* g, bf16* l) {
    __builtin_amdgcn_global_load_lds((const __attribute__((address_space(1))) void*)g,
                                     (__attribute__((address_space(3))) void*)l, 16, 0, 0);
}

// ---------------- prep: weight transpose/convert + x fp32->bf16 ----------------
// blocks 0..255: Wq, 256..319: Wk, 320..383: Wv, 384..639: Wo, 640..1151: x conversion.
__global__ __launch_bounds__(256) void prep_kernel(
    const float* __restrict__ x, const float* __restrict__ Wq, const float* __restrict__ Wk,
    const float* __restrict__ Wv, const float* __restrict__ Wo,
    bf16* __restrict__ xb, bf16* __restrict__ wqkv_t, bf16* __restrict__ wo_t)
{
    const int blk = blockIdx.x;
    const int tid = threadIdx.x;
    if (blk >= 640) {
        const float4* xv = (const float4*)x;
        const size_t base = (size_t)(blk - 640) * 2048 + tid;   // float4 units
        #pragma unroll
        for (int j = 0; j < 8; ++j) {
            const float4 v = xv[base + j * 256];
            bf16* o = xb + (base + j * 256) * 4;
            o[0] = (bf16)v.x; o[1] = (bf16)v.y; o[2] = (bf16)v.z; o[3] = (bf16)v.w;
        }
        return;
    }
    const float* W; bf16* Wt; int N, n0, k0;
    if (blk < 256)      { W = Wq; Wt = wqkv_t;                       N = 1024; n0 = (blk & 15) * 64;         k0 = (blk >> 4) * 64; }
    else if (blk < 320) { W = Wk; Wt = wqkv_t + (size_t)1024 * 1024; N = 256;  n0 = ((blk - 256) & 3) * 64;  k0 = ((blk - 256) >> 2) * 64; }
    else if (blk < 384) { W = Wv; Wt = wqkv_t + (size_t)1280 * 1024; N = 256;  n0 = ((blk - 320) & 3) * 64;  k0 = ((blk - 320) >> 2) * 64; }
    else                { W = Wo; Wt = wo_t;                         N = 1024; n0 = ((blk - 384) & 15) * 64; k0 = ((blk - 384) >> 4) * 64; }

    __shared__ float Ts[64][65];
    const int c = tid & 63, rr = tid >> 6;
    #pragma unroll
    for (int i = 0; i < 16; ++i) {
        const int kk = i * 4 + rr;
        Ts[kk][c] = W[(size_t)(k0 + kk) * N + n0 + c];
    }
    __syncthreads();
    #pragma unroll
    for (int i = 0; i < 16; ++i) {
        const int nn = i * 4 + rr;
        Wt[(size_t)(n0 + nn) * 1024 + k0 + c] = (bf16)Ts[c][nn];
    }
}

// ---------------- bf16 MFMA GEMM, SINGLE-WAVE workgroups: 64 thr, 64x64 tile, BK=32 ----
// One wave owns the whole tile: 8 gl_lds + 8 b128 reads + 16 MFMA per iter (0.5 read/MFMA,
// m97-class intensity). __syncthreads in a 1-wave block = waitcnt only -> NO barrier waits;
// latency hidden by ~6 independent blocks/CU (m114 wave overlap).
// LDS rows 32 elems (64 B); staged chunk-XOR swizzle: phys chunk p of row r holds logical
// p^((r>>1)&3); frag read at g^((li>>1)&3) -> even 8-quad bank coverage (b128 floor).
// 1D grid, XCD remap: mb = xcd*8 + k/nbc, nb = k%nbc  (nbc = N/64).
// EPI=0: C fp32 plain. EPI=2: fused RoPE + QKV split epilogue, Q pre-scaled by SM_SCALE.
template<int EPI>
__global__ __launch_bounds__(64) void gemm1w_kernel(
    const bf16* __restrict__ A, const bf16* __restrict__ Bt, float* __restrict__ C,
    const float* __restrict__ cosp, const float* __restrict__ sinp,
    bf16* __restrict__ qo, bf16* __restrict__ ko, bf16* __restrict__ vto,
    int M, int N, int K)
{
    __shared__ bf16 As[64 * 32];    // 4 KB
    __shared__ bf16 Bs[64 * 32];    // 4 KB
    const int nbc = N >> 6;
    const int xcd = blockIdx.x & 7, kidx = blockIdx.x >> 3;
    const int mb = xcd * 8 + kidx / nbc, nb = kidx % nbc;
    const int m0 = mb * 64, n0 = nb * 64;
    const int lane = threadIdx.x;
    const int g = lane >> 4, li = lane & 15;

    f32x4 acc[4][4];
    const f32x4 z = {0.f, 0.f, 0.f, 0.f};
    #pragma unroll
    for (int i = 0; i < 4; ++i)
        #pragma unroll
        for (int j = 0; j < 4; ++j) acc[i][j] = z;

    // staging: 4 calls/operand; call s covers rows s*16..s*16+15 (16 rows x 64 B = 1 KB).
    // lane l -> row s*16 + (l>>2), fetches logical chunk (l&3)^((l>>3)&3) (swizzle),
    // lands at phys chunk l&3 via HW's base+lane*16.
    const int srow = lane >> 2;
    const int schunk = ((lane & 3) ^ ((lane >> 3) & 3)) * 8;
    const bf16* pA[4]; const bf16* pB[4];
    #pragma unroll
    for (int s = 0; s < 4; ++s) {
        pA[s] = A + (size_t)(m0 + s * 16 + srow) * K + schunk;
        pB[s] = Bt + (size_t)(n0 + s * 16 + srow) * K + schunk;
    }

    for (int kk = 0; kk < K; kk += 32) {
        __syncthreads();   // 1-wave block: compiles to waitcnt, no barrier wait
        #pragma unroll
        for (int s = 0; s < 4; ++s) gl_lds16(pA[s] + kk, As + s * 512);
        #pragma unroll
        for (int s = 0; s < 4; ++s) gl_lds16(pB[s] + kk, Bs + s * 512);
        __syncthreads();

        const int phys = ((g ^ ((li >> 1) & 3)) * 8);
        bf16x8 af[4], bfr[4];
        #pragma unroll
        for (int mi = 0; mi < 4; ++mi) af[mi] = *(const bf16x8*)&As[(mi * 16 + li) * 32 + phys];
        #pragma unroll
        for (int ni = 0; ni < 4; ++ni) bfr[ni] = *(const bf16x8*)&Bs[(ni * 16 + li) * 32 + phys];
        #pragma unroll
        for (int mi = 0; mi < 4; ++mi)
            #pragma unroll
            for (int ni = 0; ni < 4; ++ni)
                acc[mi][ni] = __builtin_amdgcn_mfma_f32_16x16x32_bf16(af[mi], bfr[ni], acc[mi][ni], 0, 0, 0);
    }

    if (EPI == 0) {
        #pragma unroll
        for (int mi = 0; mi < 4; ++mi)
            #pragma unroll
            for (int ni = 0; ni < 4; ++ni)
                #pragma unroll
                for (int r = 0; r < 4; ++r)
                    C[(size_t)(m0 + mi * 16 + g * 4 + r) * N + n0 + ni * 16 + li] = acc[mi][ni][r];
    } else {
        // fused RoPE + split. cols: [0,1024) q (pre-scaled), [1024,1280) k, [1280,1536) v.
        // rotate_half partner of col is col^32 == acc[mi][ni^2][r] (same wave, in-register).
        #pragma unroll
        for (int ni = 0; ni < 4; ++ni) {
            const int col = n0 + ni * 16 + li;
            const int d = col & 63;
            #pragma unroll
            for (int mi = 0; mi < 4; ++mi) {
                #pragma unroll
                for (int r = 0; r < 4; ++r) {
                    const int row = m0 + mi * 16 + g * 4 + r;
                    const int bb = row >> 11, s = row & 2047;
                    float val = acc[mi][ni][r];
                    if (col < 1280) {
                        const float pairv = acc[mi][ni ^ 2][r];
                        const float rot = (d < 32) ? -pairv : pairv;
                        val = val * cosp[s * 64 + d] + rot * sinp[s * 64 + d];
                    }
                    if (col < 1024) {
                        const int hh = col >> 6;
                        qo[(((size_t)bb * NH + hh) * SS + s) * HD + d] = (bf16)(val * SM_SCALE);
                    } else if (col < 1280) {
                        const int kh = (col - 1024) >> 6;
                        ko[(((size_t)bb * NKV + kh) * SS + s) * HD + d] = (bf16)val;
                    } else {
                        const int kh = (col - 1280) >> 6;
                        vto[(((size_t)bb * NKV + kh) * HD + d) * SS + s] = (bf16)val;  // V^T: [d][s]
                    }
                }
            }
        }
    }
}

// ---------------- Flash attention v9 (unchanged from R13) ----------------
__global__ __launch_bounds__(256) void flash_kernel(const bf16* __restrict__ q, const bf16* __restrict__ k,
                                                    const bf16* __restrict__ vt, bf16* __restrict__ o)
{
    __shared__ bf16 Ks[128 * 64];    // 16 KB: 128 keys x 64 d, swizzled
    __shared__ bf16 Vt[64 * 128];    // 16 KB: 64 d x 128 keys, swizzled
    __shared__ bf16 Ps[4][16][64];   //  8 KB: per-wave P, column-XOR-swizzled by g

    const int blk = blockIdx.x;
    const int qt = 31 - (blk >> 5);          // heavy blocks dispatched first
    const int h = blk & 15;
    const int b = (blk >> 4) & 1;
    const int kvh = h >> 2;
    const int tid = threadIdx.x;
    const int w = tid >> 6, lane = tid & 63, g = lane >> 4, li = lane & 15;

    const bf16* qh = q + ((size_t)b * NH + h) * SS * HD;
    const bf16* kh = k + ((size_t)b * NKV + kvh) * SS * HD;
    const bf16* vh = vt + ((size_t)b * NKV + kvh) * (size_t)HD * SS;

    bf16x8 ones;
    #pragma unroll
    for (int j = 0; j < 8; ++j) ones[j] = (bf16)1.0f;
    const f32x4 z = {0.f, 0.f, 0.f, 0.f};

    const bf16* qrow = qh + (size_t)(qt * 64 + w * 16 + li) * HD;
    bf16x8 qf[2];
    qf[0] = *(const bf16x8*)(qrow + g * 8);
    qf[1] = *(const bf16x8*)(qrow + 32 + g * 8);

    const int ksrow = tid >> 3;
    const int kchunk = ((tid & 7) ^ (ksrow & 7)) * 8;
    const int vsrow = tid >> 4;
    const int vchunk = (((tid & 15) ^ (vsrow & 7)) & 15) * 8;
    bf16* lK = Ks + (size_t)w * 512;
    bf16* lV = Vt + (size_t)w * 512;

    f32x4 o_acc[4], l_acc;
    #pragma unroll
    for (int nt = 0; nt < 4; ++nt) o_acc[nt] = z;
    l_acc = z;

    for (int kt0 = 0; kt0 <= qt; kt0 += 2) {
        __syncthreads();
        {
            #pragma unroll
            for (int s = 0; s < 4; ++s)
                gl_lds16(kh + (size_t)(kt0 * 64 + s * 32 + ksrow) * HD + kchunk, lK + s * 2048);
            #pragma unroll
            for (int s = 0; s < 4; ++s)
                gl_lds16(vh + (size_t)(s * 16 + vsrow) * SS + kt0 * 64 + vchunk, lV + s * 2048);
        }
        __syncthreads();

        #pragma unroll
        for (int sub = 0; sub < 2; ++sub) {
            const int kt = kt0 + sub;
            if (kt > qt) break;

            f32x4 s_acc[4];
            #pragma unroll
            for (int nt = 0; nt < 4; ++nt) s_acc[nt] = z;
            #pragma unroll
            for (int t = 0; t < 2; ++t)
                #pragma unroll
                for (int nt = 0; nt < 4; ++nt) {
                    const bf16x8 kf = *(const bf16x8*)&Ks[(sub * 64 + nt * 16 + li) * 64 + (((t * 4 + g) ^ (li & 7)) * 8)];
                    s_acc[nt] = __builtin_amdgcn_mfma_f32_16x16x32_bf16(qf[t], kf, s_acc[nt], 0, 0, 0);
                }

            if (kt == qt) {
                const int qr0 = qt * 64 + w * 16 + g * 4;
                #pragma unroll
                for (int nt = 0; nt < 4; ++nt) {
                    const int key = kt * 64 + nt * 16 + li;
                    #pragma unroll
                    for (int r = 0; r < 4; ++r) {
                        float sv = s_acc[nt][r];
                        if (key > qr0 + r) sv = -1e30f;
                        Ps[w][g * 4 + r][(nt * 16 + li) ^ (g * 16)] = (bf16)exp2f(sv);
                    }
                }
            } else {
                #pragma unroll
                for (int nt = 0; nt < 4; ++nt)
                    #pragma unroll
                    for (int r = 0; r < 4; ++r)
                        Ps[w][g * 4 + r][(nt * 16 + li) ^ (g * 16)] = (bf16)exp2f(s_acc[nt][r]);
            }

            #pragma unroll
            for (int t = 0; t < 2; ++t) {
                const bf16x8 pf = *(const bf16x8*)&Ps[w][li][(t * 32 + g * 8) ^ ((li >> 2) * 16)];
                l_acc = __builtin_amdgcn_mfma_f32_16x16x32_bf16(pf, ones, l_acc, 0, 0, 0);
                #pragma unroll
                for (int nt = 0; nt < 4; ++nt) {
                    const bf16x8 vf = *(const bf16x8*)&Vt[(nt * 16 + li) * 128 + (((sub * 8 + t * 4 + g) ^ (li & 7)) * 8)];
                    o_acc[nt] = __builtin_amdgcn_mfma_f32_16x16x32_bf16(pf, vf, o_acc[nt], 0, 0, 0);
                }
            }
        }
    }

    #pragma unroll
    for (int r = 0; r < 4; ++r) {
        const float inv = 1.f / l_acc[r];
        const int s = qt * 64 + w * 16 + g * 4 + r;
        bf16* orow = o + (((size_t)b * SS + s) * NH + h) * HD;
        #pragma unroll
        for (int nt = 0; nt < 4; ++nt) orow[nt * 16 + li] = (bf16)(o_acc[nt][r] * inv);
    }
}

extern "C" void kernel_launch(void* const* d_in, const int* in_sizes, int n_in,
                              void* d_out, int out_size, void* d_ws, size_t ws_size,
                              hipStream_t stream) {
    const float* x     = (const float*)d_in[0];
    const float* cos_t = (const float*)d_in[1];
    const float* sin_t = (const float*)d_in[2];
    const float* Wq    = (const float*)d_in[3];
    const float* Wk    = (const float*)d_in[4];
    const float* Wv    = (const float*)d_in[5];
    const float* Wo    = (const float*)d_in[6];
    float* out = (float*)d_out;

    char* wsb = (char*)d_ws;
    bf16* x_b    = (bf16*)(wsb);                 //  8,388,608 B (aliased as o_b after QKV GEMM)
    bf16* wqkv_t = (bf16*)(wsb + 8388608);       //  3,145,728 B (1536 x 1024)
    bf16* wo_t   = (bf16*)(wsb + 11534336);      //  2,097,152 B (1024 x 1024)
    bf16* q_b    = (bf16*)(wsb + 13631488);      //  8,388,608 B
    bf16* k_b    = (bf16*)(wsb + 22020096);      //  2,097,152 B
    bf16* vt_b   = (bf16*)(wsb + 24117248);      //  2,097,152 B -> total 26,214,400 B
    bf16* o_b    = x_b;

    prep_kernel<<<1152, 256, 0, stream>>>(x, Wq, Wk, Wv, Wo, x_b, wqkv_t, wo_t);

    // QKV GEMM (single-wave blocks): 64 mb x 24 nb = 1536 blocks, XCD-remapped
    gemm1w_kernel<2><<<1536, 64, 0, stream>>>(x_b, wqkv_t, nullptr, cos_t, sin_t,
                                              q_b, k_b, vt_b, 4096, 1536, 1024);
    flash_kernel<<<1024, 256, 0, stream>>>(q_b, k_b, vt_b, o_b);
    // out-proj: 64 mb x 16 nb = 1024 blocks
    gemm1w_kernel<0><<<1024, 64, 0, stream>>>(o_b, wo_t, out, nullptr, nullptr,
                                              nullptr, nullptr, nullptr, 4096, 1024, 1024);
}